// Round 5
// baseline (400.994 us; speedup 1.0000x reference)
//
#include <hip/hip_runtime.h>
#include <hip/hip_bf16.h>

typedef __attribute__((ext_vector_type(8))) short bf16x8;
typedef __attribute__((ext_vector_type(4))) float f32x4;
typedef __attribute__((ext_vector_type(4))) short short4_t;
typedef __attribute__((ext_vector_type(8))) short short8_t;
typedef __attribute__((ext_vector_type(4))) float float4_t;

#define MFMA16(a, b, c) __builtin_amdgcn_mfma_f32_16x16x32_bf16((a), (b), (c), 0, 0, 0)

__device__ __forceinline__ unsigned short f2bf(float f) {
    unsigned u = __builtin_bit_cast(unsigned, f);
    u += 0x7fffu + ((u >> 16) & 1u);   // round-to-nearest-even
    return (unsigned short)(u >> 16);
}

__device__ __forceinline__ short4_t pack4(float4_t v) {
    short4_t r;
    r[0] = (short)f2bf(v[0]);
    r[1] = (short)f2bf(v[1]);
    r[2] = (short)f2bf(v[2]);
    r[3] = (short)f2bf(v[3]);
    return r;
}

// async global->LDS, 16B per lane. LDS dest is wave-uniform base + lane*16.
__device__ __forceinline__ void gload_lds16(const void* g, void* l) {
    __builtin_amdgcn_global_load_lds(
        (const __attribute__((address_space(1))) unsigned int*)g,
        (__attribute__((address_space(3))) unsigned int*)l, 16, 0, 0);
}

// ---------------------------------------------------------------------------
// cast: f32 -> bf16 for support (8.4M), queries (8.4M), Wq/Wk/Wv (0.5M each).
// 8 elems/thread, grid 8960 x 256 covers 18350080 elems exactly.
// ---------------------------------------------------------------------------
__global__ __launch_bounds__(256) void cast_kernel(
    const float* __restrict__ support, const float* __restrict__ queries,
    const float* __restrict__ Wq, const float* __restrict__ Wk,
    const float* __restrict__ Wv,
    unsigned short* __restrict__ sb, unsigned short* __restrict__ qb,
    unsigned short* __restrict__ wqb, unsigned short* __restrict__ wkb,
    unsigned short* __restrict__ wvb)
{
    const size_t e = ((size_t)blockIdx.x * 256 + threadIdx.x) * 8;
    const float* src; unsigned short* dst; size_t off;
    if (e < 8388608)       { src = support; dst = sb;  off = e; }
    else if (e < 16777216) { src = queries; dst = qb;  off = e - 8388608; }
    else if (e < 17301504) { src = Wq;      dst = wqb; off = e - 16777216; }
    else if (e < 17825792) { src = Wk;      dst = wkb; off = e - 17301504; }
    else                   { src = Wv;      dst = wvb; off = e - 17825792; }
    float4_t a = *(const float4_t*)(src + off);
    float4_t b = *(const float4_t*)(src + off + 4);
    short4_t lo = pack4(a), hi = pack4(b);
    short8_t o;
    o[0] = lo[0]; o[1] = lo[1]; o[2] = lo[2]; o[3] = lo[3];
    o[4] = hi[0]; o[5] = hi[1]; o[6] = hi[2]; o[7] = hi[3];
    *(short8_t*)(dst + off) = o;
}

// ---------------------------------------------------------------------------
// proj_v: out = in @ Wv^T + bv, modes {0: queries->q_proto f32, 1: support->
// VsT bf16 transposed}. bf16 inputs, global_load_lds staging (XOR-preswizzle).
// BM=128, BN=256, BK=64, 16 kt, dbuf, single barrier/kt.
// Wave grid 2r x 4c: acc[4][4]. LDS 2*(16+32)=96KB.
// ---------------------------------------------------------------------------
__global__ __launch_bounds__(512, 2) void proj_v_kernel(
    const unsigned short* __restrict__ sb, const unsigned short* __restrict__ qb,
    const unsigned short* __restrict__ wvb, const float* __restrict__ bv,
    float* __restrict__ q_proto, unsigned short* __restrict__ VsT)
{
    const int mode = blockIdx.x >> 7;
    const int rem = blockIdx.x & 127;
    const int rowbase = (rem >> 1) * 128;
    const int colbase = (rem & 1) * 256;
    const unsigned short* A = mode ? sb : qb;

    const int t = threadIdx.x;
    const int w = t >> 6, l = t & 63, lg = l >> 4, ll = l & 15;
    const int wr = w & 1, wc = w >> 1;
    const int sr = l >> 3, su = l & 7;   // staging: lane -> row-in-octet, unit

    __shared__ unsigned short Alds[2][128][64];
    __shared__ unsigned short Blds[2][256][64];

    f32x4 acc[4][4];
    #pragma unroll
    for (int i = 0; i < 4; ++i)
        #pragma unroll
        for (int j = 0; j < 4; ++j) acc[i][j] = (f32x4){0.f, 0.f, 0.f, 0.f};

    // stage tile kt into buf: A rows w*16..+16 (2 gloads), B rows w*32..+32 (4)
    #define PV_STAGE(buf, kt)                                                   \
        {                                                                       \
            const int kc = (kt) * 64;                                           \
            _Pragma("unroll")                                                   \
            for (int g = 0; g < 2; ++g) {                                       \
                const int r0 = w * 16 + g * 8, row = r0 + sr;                   \
                gload_lds16(A + (size_t)(rowbase + row) * 1024 + kc             \
                                + ((su ^ (row & 7)) << 3),                      \
                            &Alds[buf][r0][0]);                                 \
            }                                                                   \
            _Pragma("unroll")                                                   \
            for (int g = 0; g < 4; ++g) {                                       \
                const int r0 = w * 32 + g * 8, row = r0 + sr;                   \
                gload_lds16(wvb + (size_t)(colbase + row) * 1024 + kc           \
                                + ((su ^ (row & 7)) << 3),                      \
                            &Blds[buf][r0][0]);                                 \
            }                                                                   \
        }

    PV_STAGE(0, 0)
    __syncthreads();

    for (int kt = 0; kt < 16; ++kt) {
        const int cur = kt & 1;
        if (kt < 15) PV_STAGE(cur ^ 1, kt + 1)
        #pragma unroll
        for (int ks = 0; ks < 2; ++ks) {
            const int u = ((ks * 4 + lg) ^ (ll & 7)) * 8;
            bf16x8 af[4], bfr[4];
            #pragma unroll
            for (int mf = 0; mf < 4; ++mf)
                af[mf] = *(const bf16x8*)&Alds[cur][wr * 64 + mf * 16 + ll][u];
            #pragma unroll
            for (int nf = 0; nf < 4; ++nf)
                bfr[nf] = *(const bf16x8*)&Blds[cur][wc * 64 + nf * 16 + ll][u];
            #pragma unroll
            for (int mf = 0; mf < 4; ++mf)
                #pragma unroll
                for (int nf = 0; nf < 4; ++nf)
                    acc[mf][nf] = MFMA16(af[mf], bfr[nf], acc[mf][nf]);
        }
        __syncthreads();
    }
    #undef PV_STAGE

    float bvv[4];
    #pragma unroll
    for (int nf = 0; nf < 4; ++nf) bvv[nf] = bv[colbase + wc * 64 + nf * 16 + ll];

    if (mode == 0) {
        #pragma unroll
        for (int mf = 0; mf < 4; ++mf)
            #pragma unroll
            for (int r = 0; r < 4; ++r) {
                const size_t row = rowbase + wr * 64 + mf * 16 + lg * 4 + r;
                #pragma unroll
                for (int nf = 0; nf < 4; ++nf)
                    q_proto[row * 512 + colbase + wc * 64 + nf * 16 + ll] = acc[mf][nf][r] + bvv[nf];
            }
    } else {
        #pragma unroll
        for (int mf = 0; mf < 4; ++mf)
            #pragma unroll
            for (int nf = 0; nf < 4; ++nf) {
                float4_t pv = {acc[mf][nf][0] + bvv[nf], acc[mf][nf][1] + bvv[nf],
                               acc[mf][nf][2] + bvv[nf], acc[mf][nf][3] + bvv[nf]};
                const size_t col = colbase + wc * 64 + nf * 16 + ll;
                *(short4_t*)&VsT[col * 8192 + rowbase + wr * 64 + mf * 16 + lg * 4] = pack4(pv);
            }
    }
}

// ---------------------------------------------------------------------------
// proj_ln: dst = LN(in @ W^T + b), modes {0: support/Wk->Ks, 1: queries/Wq->Qs}.
// bf16 inputs, gload staging. BM=64, BN=512, BK=64, 16 kt, dbuf.
// Wave grid 1r x 8c: wave owns all 64 rows x 64 cols -> acc[4][4]; the big
// B panel has zero cross-wave read redundancy. LDS 2*(8+64)=144KB + red.
// ---------------------------------------------------------------------------
__global__ __launch_bounds__(512, 2) void proj_ln_kernel(
    const unsigned short* __restrict__ sb, const unsigned short* __restrict__ qb,
    const unsigned short* __restrict__ wkb, const float* __restrict__ bk,
    const unsigned short* __restrict__ wqb, const float* __restrict__ bq,
    const float* __restrict__ gamma, const float* __restrict__ beta,
    unsigned short* __restrict__ Ks, unsigned short* __restrict__ Qs)
{
    const int mode = blockIdx.x >> 7;
    const int rowbase = (blockIdx.x & 127) * 64;
    const unsigned short* A = mode ? qb : sb;
    const unsigned short* W = mode ? wqb : wkb;
    const float* bias = mode ? bq : bk;
    unsigned short* dst = mode ? Qs : Ks;

    const int t = threadIdx.x;
    const int w = t >> 6, l = t & 63, lg = l >> 4, ll = l & 15;
    const int sr = l >> 3, su = l & 7;

    __shared__ unsigned short Alds[2][64][64];    // 16 KB
    __shared__ unsigned short Blds[2][512][64];   // 128 KB
    __shared__ float red[8][64][2];               // 4 KB
    __shared__ float stats[64][2];

    f32x4 acc[4][4];
    #pragma unroll
    for (int i = 0; i < 4; ++i)
        #pragma unroll
        for (int j = 0; j < 4; ++j) acc[i][j] = (f32x4){0.f, 0.f, 0.f, 0.f};

    #define LN_STAGE(buf, kt)                                                   \
        {                                                                       \
            const int kc = (kt) * 64;                                           \
            {                                                                   \
                const int r0 = w * 8, row = r0 + sr;                            \
                gload_lds16(A + (size_t)(rowbase + row) * 1024 + kc             \
                                + ((su ^ (row & 7)) << 3),                      \
                            &Alds[buf][r0][0]);                                 \
            }                                                                   \
            _Pragma("unroll")                                                   \
            for (int g = 0; g < 8; ++g) {                                       \
                const int r0 = w * 64 + g * 8, row = r0 + sr;                   \
                gload_lds16(W + (size_t)row * 1024 + kc                         \
                                + ((su ^ (row & 7)) << 3),                      \
                            &Blds[buf][r0][0]);                                 \
            }                                                                   \
        }

    LN_STAGE(0, 0)
    __syncthreads();

    for (int kt = 0; kt < 16; ++kt) {
        const int cur = kt & 1;
        if (kt < 15) LN_STAGE(cur ^ 1, kt + 1)
        #pragma unroll
        for (int ks = 0; ks < 2; ++ks) {
            const int u = ((ks * 4 + lg) ^ (ll & 7)) * 8;
            bf16x8 af[4], bfr[4];
            #pragma unroll
            for (int mf = 0; mf < 4; ++mf)
                af[mf] = *(const bf16x8*)&Alds[cur][mf * 16 + ll][u];
            #pragma unroll
            for (int nf = 0; nf < 4; ++nf)
                bfr[nf] = *(const bf16x8*)&Blds[cur][w * 64 + nf * 16 + ll][u];
            #pragma unroll
            for (int mf = 0; mf < 4; ++mf)
                #pragma unroll
                for (int nf = 0; nf < 4; ++nf)
                    acc[mf][nf] = MFMA16(af[mf], bfr[nf], acc[mf][nf]);
        }
        __syncthreads();
    }
    #undef LN_STAGE

    float bvv[4];
    #pragma unroll
    for (int nf = 0; nf < 4; ++nf) bvv[nf] = bias[w * 64 + nf * 16 + ll];

    float v[4][4][4];
    #pragma unroll
    for (int mf = 0; mf < 4; ++mf)
        #pragma unroll
        for (int nf = 0; nf < 4; ++nf)
            #pragma unroll
            for (int r = 0; r < 4; ++r)
                v[mf][nf][r] = acc[mf][nf][r] + bvv[nf];

    // per-wave partial row sums over this wave's 64 cols
    #pragma unroll
    for (int mf = 0; mf < 4; ++mf)
        #pragma unroll
        for (int r = 0; r < 4; ++r) {
            float s = 0.f, q = 0.f;
            #pragma unroll
            for (int nf = 0; nf < 4; ++nf) { s += v[mf][nf][r]; q += v[mf][nf][r] * v[mf][nf][r]; }
            #pragma unroll
            for (int d = 1; d < 16; d <<= 1) { s += __shfl_xor(s, d); q += __shfl_xor(q, d); }
            if (ll == 0) {
                red[w][mf * 16 + lg * 4 + r][0] = s;
                red[w][mf * 16 + lg * 4 + r][1] = q;
            }
        }
    __syncthreads();
    if (t < 64) {
        float S = 0.f, Q = 0.f;
        #pragma unroll
        for (int w2 = 0; w2 < 8; ++w2) { S += red[w2][t][0]; Q += red[w2][t][1]; }
        const float mu = S * (1.f / 512.f);
        const float var = Q * (1.f / 512.f) - mu * mu;
        stats[t][0] = mu;
        stats[t][1] = rsqrtf(var + 1e-5f);
    }
    __syncthreads();
    float gv[4], bev[4];
    #pragma unroll
    for (int nf = 0; nf < 4; ++nf) {
        gv[nf] = gamma[w * 64 + nf * 16 + ll];
        bev[nf] = beta[w * 64 + nf * 16 + ll];
    }
    #pragma unroll
    for (int mf = 0; mf < 4; ++mf)
        #pragma unroll
        for (int r = 0; r < 4; ++r) {
            const int row = mf * 16 + lg * 4 + r;
            const float mu = stats[row][0], rs = stats[row][1];
            #pragma unroll
            for (int nf = 0; nf < 4; ++nf) {
                const float o = (v[mf][nf][r] - mu) * rs * gv[nf] + bev[nf];
                dst[(size_t)(rowbase + row) * 512 + w * 64 + nf * 16 + ll] = f2bf(o);
            }
        }
}

// ---------------------------------------------------------------------------
// Flash attention v5: BM=64, BKV=64, kv-split 2, grid 256, 8 waves.
// QK^T wave grid 2q x 4kv: wave holds TWO Q fragments (qf[2][16], 128 VGPR)
// so each K ds_read_b128 feeds 2 MFMAs -> K-read count halved vs v4.
// PV wave grid 1r x 8c (unchanged). Single barrier/iter, K+P double-buffered.
// LDS: 128KB K + 16KB P + 1KB lsum.
// ---------------------------------------------------------------------------
__global__ __launch_bounds__(512, 2) void attn_kernel(
    const unsigned short* __restrict__ Qs, const unsigned short* __restrict__ Ks,
    const unsigned short* __restrict__ VsT,
    float* __restrict__ Opart, float* __restrict__ lpart)
{
    const int bid = blockIdx.x;
    const int sp = (bid & 7) >> 2;              // kv half pinned per XCD group
    const int qb = (bid >> 3) * 4 + (bid & 3);  // 0..127
    const int qbase = qb * 64;
    const int kv0 = sp * 4096;
    const int t = threadIdx.x;
    const int w = t >> 6, l = t & 63, lg = l >> 4, ll = l & 15;
    const int wq2 = w & 1, wk4 = w >> 1;        // QK^T decomposition 2q x 4kv

    __shared__ unsigned short Klds[2][64][512];   // 128 KB, src-preswizzled
    __shared__ unsigned short Plds[2][64][64];    // 16 KB, (row>>1)&7 swizzled
    __shared__ float lsum[4][64];

    // TWO Q fragment rows per wave: rows qbase + wq2*32 + {0,16} + ll
    bf16x8 qf[2][16];
    #pragma unroll
    for (int mf = 0; mf < 2; ++mf) {
        const unsigned short* qrow = Qs + (size_t)(qbase + wq2 * 32 + mf * 16 + ll) * 512 + lg * 8;
        #pragma unroll
        for (int ks = 0; ks < 16; ++ks)
            qf[mf][ks] = *(const bf16x8*)(qrow + ks * 32);
    }

    f32x4 oacc[4][4];
    #pragma unroll
    for (int i = 0; i < 4; ++i)
        #pragma unroll
        for (int j = 0; j < 4; ++j) oacc[i][j] = (f32x4){0.f, 0.f, 0.f, 0.f};
    float lrun[2][4];
    #pragma unroll
    for (int i = 0; i < 2; ++i)
        #pragma unroll
        for (int j = 0; j < 4; ++j) lrun[i][j] = 0.f;
    const float scale = 0.044194173824159216f;  // 1/sqrt(512)

    #pragma unroll
    for (int rr = 0; rr < 8; ++rr) {
        const int r = w * 8 + rr;
        gload_lds16(Ks + (size_t)(kv0 + r) * 512 + ((l ^ (r & 7)) << 3),
                    &Klds[0][r][0]);
    }
    __syncthreads();

    for (int it = 0; it < 64; ++it) {
        const int cur = it & 1;
        const int kvb = kv0 + it * 64;

        if (it < 63) {
            const int kvn = kvb + 64;
            #pragma unroll
            for (int rr = 0; rr < 8; ++rr) {
                const int r = w * 8 + rr;
                gload_lds16(Ks + (size_t)(kvn + r) * 512 + ((l ^ (r & 7)) << 3),
                            &Klds[cur ^ 1][r][0]);
            }
        }

        // QK^T: wave (wq2, wk4): q-rows wq2*32..+32, kv-cols wk4*16..+16
        f32x4 sacc[2];
        sacc[0] = (f32x4){0.f, 0.f, 0.f, 0.f};
        sacc[1] = (f32x4){0.f, 0.f, 0.f, 0.f};
        __builtin_amdgcn_s_setprio(1);
        #pragma unroll
        for (int ks = 0; ks < 16; ++ks) {
            const int u = ((ks * 4 + lg) ^ (ll & 7)) * 8;
            bf16x8 kf = *(const bf16x8*)&Klds[cur][wk4 * 16 + ll][u];
            sacc[0] = MFMA16(qf[0][ks], kf, sacc[0]);
            sacc[1] = MFMA16(qf[1][ks], kf, sacc[1]);
        }
        __builtin_amdgcn_s_setprio(0);

        // exp + P write into P[cur]
        #pragma unroll
        for (int mf = 0; mf < 2; ++mf)
            #pragma unroll
            for (int r = 0; r < 4; ++r) {
                const int row = wq2 * 32 + mf * 16 + lg * 4 + r;
                const int swz = (row >> 1) & 7;
                const float p = __expf(sacc[mf][r] * scale);
                const int col = wk4 * 16 + ll;
                const int unit = (col >> 3) ^ swz;
                Plds[cur][row][unit * 8 + (col & 7)] = f2bf(p);
                float rsum = p;
                #pragma unroll
                for (int d = 1; d < 16; d <<= 1) rsum += __shfl_xor(rsum, d);
                lrun[mf][r] += rsum;   // partial over this wave's 16 kv cols
            }

        __syncthreads();   // P[cur] ready, K[cur^1] staged

        // PV: wave w owns out-cols w*64..+64, all 64 q-rows
        __builtin_amdgcn_s_setprio(1);
        #pragma unroll
        for (int ks2 = 0; ks2 < 2; ++ks2) {
            bf16x8 vf[4];
            #pragma unroll
            for (int nf = 0; nf < 4; ++nf)
                vf[nf] = *(const bf16x8*)(VsT + (size_t)(w * 64 + nf * 16 + ll) * 8192
                                          + kvb + ks2 * 32 + lg * 8);
            #pragma unroll
            for (int mf = 0; mf < 4; ++mf) {
                const int row = mf * 16 + ll;
                const int unit = (ks2 * 4 + lg) ^ ((row >> 1) & 7);
                bf16x8 pf = *(const bf16x8*)&Plds[cur][row][unit * 8];
                #pragma unroll
                for (int nf = 0; nf < 4; ++nf)
                    oacc[mf][nf] = MFMA16(pf, vf[nf], oacc[mf][nf]);
            }
        }
        __builtin_amdgcn_s_setprio(0);
    }

    const size_t obase = (size_t)sp * 8192 + qbase;
    #pragma unroll
    for (int mf = 0; mf < 4; ++mf)
        #pragma unroll
        for (int r = 0; r < 4; ++r) {
            const size_t row = obase + mf * 16 + lg * 4 + r;
            #pragma unroll
            for (int nf = 0; nf < 4; ++nf)
                Opart[row * 512 + w * 64 + nf * 16 + ll] = oacc[mf][nf][r];
        }
    if (ll == 0) {
        #pragma unroll
        for (int mf = 0; mf < 2; ++mf)
            #pragma unroll
            for (int r = 0; r < 4; ++r)
                lsum[wk4][wq2 * 32 + mf * 16 + lg * 4 + r] = lrun[mf][r];
    }
    __syncthreads();
    if (t < 64)
        lpart[(size_t)sp * 8192 + qbase + t] =
            lsum[0][t] + lsum[1][t] + lsum[2][t] + lsum[3][t];
}

// ---------------------------------------------------------------------------
// Merge: out2 = (sum_s Opart[s]) / (sum_s lpart[s]), s in {0,1}
// ---------------------------------------------------------------------------
__global__ __launch_bounds__(256) void merge_kernel(
    const float* __restrict__ Opart, const float* __restrict__ lpart,
    float* __restrict__ out2)
{
    const int idx = blockIdx.x * 256 + threadIdx.x;
    const int q = idx >> 7;
    const int c = (idx & 127) * 4;
    float4_t a = {0.f, 0.f, 0.f, 0.f};
    float ls = 0.f;
    #pragma unroll
    for (int s = 0; s < 2; ++s) {
        float4_t vv = *(const float4_t*)(Opart + ((size_t)s * 8192 + q) * 512 + c);
        a += vv;
        ls += lpart[s * 8192 + q];
    }
    const float inv = 1.f / ls;
    *(float4_t*)(out2 + (size_t)q * 512 + c) = a * inv;
}

extern "C" void kernel_launch(void* const* d_in, const int* in_sizes, int n_in,
                              void* d_out, int out_size, void* d_ws, size_t ws_size,
                              hipStream_t stream)
{
    const float* support = (const float*)d_in[0];
    const float* queries = (const float*)d_in[1];
    const float* Wq = (const float*)d_in[2];
    const float* bq = (const float*)d_in[3];
    const float* Wk = (const float*)d_in[4];
    const float* bk = (const float*)d_in[5];
    const float* Wv = (const float*)d_in[6];
    const float* bv = (const float*)d_in[7];
    const float* gamma = (const float*)d_in[8];
    const float* beta = (const float*)d_in[9];

    float* out = (float*)d_out;
    float* q_proto = out;                       // output 0: [8192,512]
    float* out2 = out + (size_t)8192 * 512;     // output 1: [8192,512]

    char* ws = (char*)d_ws;
    unsigned short* Qs  = (unsigned short*)(ws);                      //  0..8 MB
    unsigned short* Ks  = (unsigned short*)(ws + ((size_t)8 << 20));  //  8..16
    unsigned short* VsT = (unsigned short*)(ws + ((size_t)16 << 20)); // 16..24
    unsigned short* sb  = (unsigned short*)(ws + ((size_t)24 << 20)); // 24..40
    unsigned short* qbuf= (unsigned short*)(ws + ((size_t)40 << 20)); // 40..56
    unsigned short* wqb = (unsigned short*)(ws + ((size_t)56 << 20)); // 56..57
    unsigned short* wkb = (unsigned short*)(ws + ((size_t)57 << 20)); // 57..58
    unsigned short* wvb = (unsigned short*)(ws + ((size_t)58 << 20)); // 58..59
    // Opart aliases sb/qbuf (24..56 MB): proj kernels (sole readers of sb/qbuf)
    // complete before attn writes Opart; cast re-fills sb/qbuf every call.
    float* Opart = (float*)(ws + ((size_t)24 << 20));                 // 32 MB
    float* lpart = (float*)(ws + ((size_t)59 << 20));                 // 64 KB

    cast_kernel<<<8960, 256, 0, stream>>>(support, queries, Wq, Wk, Wv,
                                          sb, qbuf, wqb, wkb, wvb);
    proj_v_kernel<<<256, 512, 0, stream>>>(sb, qbuf, wvb, bv, q_proto, VsT);
    proj_ln_kernel<<<256, 512, 0, stream>>>(sb, qbuf, wkb, bk, wqb, bq,
                                            gamma, beta, Ks, Qs);
    attn_kernel<<<256, 512, 0, stream>>>(Qs, Ks, VsT, Opart, lpart);
    merge_kernel<<<4096, 256, 0, stream>>>(Opart, lpart, out2);
}

// Round 6
// 361.698 us; speedup vs baseline: 1.1086x; 1.1086x over previous
//
#include <hip/hip_runtime.h>
#include <hip/hip_bf16.h>

typedef __attribute__((ext_vector_type(8))) short bf16x8;
typedef __attribute__((ext_vector_type(4))) float f32x4;
typedef __attribute__((ext_vector_type(4))) short short4_t;
typedef __attribute__((ext_vector_type(8))) short short8_t;
typedef __attribute__((ext_vector_type(4))) float float4_t;

#define MFMA16(a, b, c) __builtin_amdgcn_mfma_f32_16x16x32_bf16((a), (b), (c), 0, 0, 0)

__device__ __forceinline__ unsigned short f2bf(float f) {
    unsigned u = __builtin_bit_cast(unsigned, f);
    u += 0x7fffu + ((u >> 16) & 1u);   // round-to-nearest-even
    return (unsigned short)(u >> 16);
}

__device__ __forceinline__ short4_t pack4(float4_t v) {
    short4_t r;
    r[0] = (short)f2bf(v[0]);
    r[1] = (short)f2bf(v[1]);
    r[2] = (short)f2bf(v[2]);
    r[3] = (short)f2bf(v[3]);
    return r;
}

// async global->LDS, 16B per lane. LDS dest is wave-uniform base + lane*16.
__device__ __forceinline__ void gload_lds16(const void* g, void* l) {
    __builtin_amdgcn_global_load_lds(
        (const __attribute__((address_space(1))) unsigned int*)g,
        (__attribute__((address_space(3))) unsigned int*)l, 16, 0, 0);
}

// ---------------------------------------------------------------------------
// cast: f32 -> bf16 for support (8.4M), queries (8.4M), Wq/Wk/Wv (0.5M each).
// 8 elems/thread, grid 8960 x 256 covers 18350080 elems exactly.
// ---------------------------------------------------------------------------
__global__ __launch_bounds__(256) void cast_kernel(
    const float* __restrict__ support, const float* __restrict__ queries,
    const float* __restrict__ Wq, const float* __restrict__ Wk,
    const float* __restrict__ Wv,
    unsigned short* __restrict__ sb, unsigned short* __restrict__ qb,
    unsigned short* __restrict__ wqb, unsigned short* __restrict__ wkb,
    unsigned short* __restrict__ wvb)
{
    const size_t e = ((size_t)blockIdx.x * 256 + threadIdx.x) * 8;
    const float* src; unsigned short* dst; size_t off;
    if (e < 8388608)       { src = support; dst = sb;  off = e; }
    else if (e < 16777216) { src = queries; dst = qb;  off = e - 8388608; }
    else if (e < 17301504) { src = Wq;      dst = wqb; off = e - 16777216; }
    else if (e < 17825792) { src = Wk;      dst = wkb; off = e - 17301504; }
    else                   { src = Wv;      dst = wvb; off = e - 17825792; }
    float4_t a = *(const float4_t*)(src + off);
    float4_t b = *(const float4_t*)(src + off + 4);
    short4_t lo = pack4(a), hi = pack4(b);
    short8_t o;
    o[0] = lo[0]; o[1] = lo[1]; o[2] = lo[2]; o[3] = lo[3];
    o[4] = hi[0]; o[5] = hi[1]; o[6] = hi[2]; o[7] = hi[3];
    *(short8_t*)(dst + off) = o;
}

// ---------------------------------------------------------------------------
// proj_v: out = in @ Wv^T + bv, modes {0: queries->q_proto f32, 1: support->
// VsT bf16 transposed}. bf16 inputs, global_load_lds staging (XOR-preswizzle).
// BM=128, BN=256, BK=64, 16 kt, dbuf, single barrier/kt.
// Wave grid 2r x 4c: acc[4][4]. LDS 2*(16+32)=96KB.
// ---------------------------------------------------------------------------
__global__ __launch_bounds__(512, 2) void proj_v_kernel(
    const unsigned short* __restrict__ sb, const unsigned short* __restrict__ qb,
    const unsigned short* __restrict__ wvb, const float* __restrict__ bv,
    float* __restrict__ q_proto, unsigned short* __restrict__ VsT)
{
    const int mode = blockIdx.x >> 7;
    const int rem = blockIdx.x & 127;
    const int rowbase = (rem >> 1) * 128;
    const int colbase = (rem & 1) * 256;
    const unsigned short* A = mode ? sb : qb;

    const int t = threadIdx.x;
    const int w = t >> 6, l = t & 63, lg = l >> 4, ll = l & 15;
    const int wr = w & 1, wc = w >> 1;
    const int sr = l >> 3, su = l & 7;   // staging: lane -> row-in-octet, unit

    __shared__ unsigned short Alds[2][128][64];
    __shared__ unsigned short Blds[2][256][64];

    f32x4 acc[4][4];
    #pragma unroll
    for (int i = 0; i < 4; ++i)
        #pragma unroll
        for (int j = 0; j < 4; ++j) acc[i][j] = (f32x4){0.f, 0.f, 0.f, 0.f};

    #define PV_STAGE(buf, kt)                                                   \
        {                                                                       \
            const int kc = (kt) * 64;                                           \
            _Pragma("unroll")                                                   \
            for (int g = 0; g < 2; ++g) {                                       \
                const int r0 = w * 16 + g * 8, row = r0 + sr;                   \
                gload_lds16(A + (size_t)(rowbase + row) * 1024 + kc             \
                                + ((su ^ (row & 7)) << 3),                      \
                            &Alds[buf][r0][0]);                                 \
            }                                                                   \
            _Pragma("unroll")                                                   \
            for (int g = 0; g < 4; ++g) {                                       \
                const int r0 = w * 32 + g * 8, row = r0 + sr;                   \
                gload_lds16(wvb + (size_t)(colbase + row) * 1024 + kc           \
                                + ((su ^ (row & 7)) << 3),                      \
                            &Blds[buf][r0][0]);                                 \
            }                                                                   \
        }

    PV_STAGE(0, 0)
    __syncthreads();

    for (int kt = 0; kt < 16; ++kt) {
        const int cur = kt & 1;
        if (kt < 15) PV_STAGE(cur ^ 1, kt + 1)
        #pragma unroll
        for (int ks = 0; ks < 2; ++ks) {
            const int u = ((ks * 4 + lg) ^ (ll & 7)) * 8;
            bf16x8 af[4], bfr[4];
            #pragma unroll
            for (int mf = 0; mf < 4; ++mf)
                af[mf] = *(const bf16x8*)&Alds[cur][wr * 64 + mf * 16 + ll][u];
            #pragma unroll
            for (int nf = 0; nf < 4; ++nf)
                bfr[nf] = *(const bf16x8*)&Blds[cur][wc * 64 + nf * 16 + ll][u];
            #pragma unroll
            for (int mf = 0; mf < 4; ++mf)
                #pragma unroll
                for (int nf = 0; nf < 4; ++nf)
                    acc[mf][nf] = MFMA16(af[mf], bfr[nf], acc[mf][nf]);
        }
        __syncthreads();
    }
    #undef PV_STAGE

    float bvv[4];
    #pragma unroll
    for (int nf = 0; nf < 4; ++nf) bvv[nf] = bv[colbase + wc * 64 + nf * 16 + ll];

    if (mode == 0) {
        #pragma unroll
        for (int mf = 0; mf < 4; ++mf)
            #pragma unroll
            for (int r = 0; r < 4; ++r) {
                const size_t row = rowbase + wr * 64 + mf * 16 + lg * 4 + r;
                #pragma unroll
                for (int nf = 0; nf < 4; ++nf)
                    q_proto[row * 512 + colbase + wc * 64 + nf * 16 + ll] = acc[mf][nf][r] + bvv[nf];
            }
    } else {
        #pragma unroll
        for (int mf = 0; mf < 4; ++mf)
            #pragma unroll
            for (int nf = 0; nf < 4; ++nf) {
                float4_t pv = {acc[mf][nf][0] + bvv[nf], acc[mf][nf][1] + bvv[nf],
                               acc[mf][nf][2] + bvv[nf], acc[mf][nf][3] + bvv[nf]};
                const size_t col = colbase + wc * 64 + nf * 16 + ll;
                *(short4_t*)&VsT[col * 8192 + rowbase + wr * 64 + mf * 16 + lg * 4] = pack4(pv);
            }
    }
}

// ---------------------------------------------------------------------------
// proj_ln: dst = LN(in @ W^T + b), modes {0: support/Wk->Ks, 1: queries/Wq->Qs}.
// bf16 inputs, gload staging. BM=64, BN=512, BK=64, 16 kt, dbuf.
// Wave grid 1r x 8c: acc[4][4]; B panel has zero cross-wave redundancy.
// ---------------------------------------------------------------------------
__global__ __launch_bounds__(512, 2) void proj_ln_kernel(
    const unsigned short* __restrict__ sb, const unsigned short* __restrict__ qb,
    const unsigned short* __restrict__ wkb, const float* __restrict__ bk,
    const unsigned short* __restrict__ wqb, const float* __restrict__ bq,
    const float* __restrict__ gamma, const float* __restrict__ beta,
    unsigned short* __restrict__ Ks, unsigned short* __restrict__ Qs)
{
    const int mode = blockIdx.x >> 7;
    const int rowbase = (blockIdx.x & 127) * 64;
    const unsigned short* A = mode ? qb : sb;
    const unsigned short* W = mode ? wqb : wkb;
    const float* bias = mode ? bq : bk;
    unsigned short* dst = mode ? Qs : Ks;

    const int t = threadIdx.x;
    const int w = t >> 6, l = t & 63, lg = l >> 4, ll = l & 15;
    const int sr = l >> 3, su = l & 7;

    __shared__ unsigned short Alds[2][64][64];    // 16 KB
    __shared__ unsigned short Blds[2][512][64];   // 128 KB
    __shared__ float red[8][64][2];               // 4 KB
    __shared__ float stats[64][2];

    f32x4 acc[4][4];
    #pragma unroll
    for (int i = 0; i < 4; ++i)
        #pragma unroll
        for (int j = 0; j < 4; ++j) acc[i][j] = (f32x4){0.f, 0.f, 0.f, 0.f};

    #define LN_STAGE(buf, kt)                                                   \
        {                                                                       \
            const int kc = (kt) * 64;                                           \
            {                                                                   \
                const int r0 = w * 8, row = r0 + sr;                            \
                gload_lds16(A + (size_t)(rowbase + row) * 1024 + kc             \
                                + ((su ^ (row & 7)) << 3),                      \
                            &Alds[buf][r0][0]);                                 \
            }                                                                   \
            _Pragma("unroll")                                                   \
            for (int g = 0; g < 8; ++g) {                                       \
                const int r0 = w * 64 + g * 8, row = r0 + sr;                   \
                gload_lds16(W + (size_t)row * 1024 + kc                         \
                                + ((su ^ (row & 7)) << 3),                      \
                            &Blds[buf][r0][0]);                                 \
            }                                                                   \
        }

    LN_STAGE(0, 0)
    __syncthreads();

    for (int kt = 0; kt < 16; ++kt) {
        const int cur = kt & 1;
        if (kt < 15) LN_STAGE(cur ^ 1, kt + 1)
        #pragma unroll
        for (int ks = 0; ks < 2; ++ks) {
            const int u = ((ks * 4 + lg) ^ (ll & 7)) * 8;
            bf16x8 af[4], bfr[4];
            #pragma unroll
            for (int mf = 0; mf < 4; ++mf)
                af[mf] = *(const bf16x8*)&Alds[cur][mf * 16 + ll][u];
            #pragma unroll
            for (int nf = 0; nf < 4; ++nf)
                bfr[nf] = *(const bf16x8*)&Blds[cur][w * 64 + nf * 16 + ll][u];
            #pragma unroll
            for (int mf = 0; mf < 4; ++mf)
                #pragma unroll
                for (int nf = 0; nf < 4; ++nf)
                    acc[mf][nf] = MFMA16(af[mf], bfr[nf], acc[mf][nf]);
        }
        __syncthreads();
    }
    #undef LN_STAGE

    float bvv[4];
    #pragma unroll
    for (int nf = 0; nf < 4; ++nf) bvv[nf] = bias[w * 64 + nf * 16 + ll];

    float v[4][4][4];
    #pragma unroll
    for (int mf = 0; mf < 4; ++mf)
        #pragma unroll
        for (int nf = 0; nf < 4; ++nf)
            #pragma unroll
            for (int r = 0; r < 4; ++r)
                v[mf][nf][r] = acc[mf][nf][r] + bvv[nf];

    #pragma unroll
    for (int mf = 0; mf < 4; ++mf)
        #pragma unroll
        for (int r = 0; r < 4; ++r) {
            float s = 0.f, q = 0.f;
            #pragma unroll
            for (int nf = 0; nf < 4; ++nf) { s += v[mf][nf][r]; q += v[mf][nf][r] * v[mf][nf][r]; }
            #pragma unroll
            for (int d = 1; d < 16; d <<= 1) { s += __shfl_xor(s, d); q += __shfl_xor(q, d); }
            if (ll == 0) {
                red[w][mf * 16 + lg * 4 + r][0] = s;
                red[w][mf * 16 + lg * 4 + r][1] = q;
            }
        }
    __syncthreads();
    if (t < 64) {
        float S = 0.f, Q = 0.f;
        #pragma unroll
        for (int w2 = 0; w2 < 8; ++w2) { S += red[w2][t][0]; Q += red[w2][t][1]; }
        const float mu = S * (1.f / 512.f);
        const float var = Q * (1.f / 512.f) - mu * mu;
        stats[t][0] = mu;
        stats[t][1] = rsqrtf(var + 1e-5f);
    }
    __syncthreads();
    float gv[4], bev[4];
    #pragma unroll
    for (int nf = 0; nf < 4; ++nf) {
        gv[nf] = gamma[w * 64 + nf * 16 + ll];
        bev[nf] = beta[w * 64 + nf * 16 + ll];
    }
    #pragma unroll
    for (int mf = 0; mf < 4; ++mf)
        #pragma unroll
        for (int r = 0; r < 4; ++r) {
            const int row = mf * 16 + lg * 4 + r;
            const float mu = stats[row][0], rs = stats[row][1];
            #pragma unroll
            for (int nf = 0; nf < 4; ++nf) {
                const float o = (v[mf][nf][r] - mu) * rs * gv[nf] + bev[nf];
                dst[(size_t)(rowbase + row) * 512 + w * 64 + nf * 16 + ll] = f2bf(o);
            }
        }
}

// ---------------------------------------------------------------------------
// Flash attention v6 = v5 structure with the register cap fixed.
// __launch_bounds__(512, 1): LDS (145KB) caps us at 1 block/CU regardless, so
// allow the full 256 VGPR/wave -> qf[2][16] (128 VGPR) stays in registers
// (v5's (512,2) capped at 128 VGPR and spilled ~100 regs to scratch).
// QK^T wave grid 2q x 4kv: each K ds_read feeds 2 MFMAs.
// Softmax row-sum: accumulate per-lane, single shuffle-reduce after the loop.
// ---------------------------------------------------------------------------
__global__ __launch_bounds__(512, 1) void attn_kernel(
    const unsigned short* __restrict__ Qs, const unsigned short* __restrict__ Ks,
    const unsigned short* __restrict__ VsT,
    float* __restrict__ Opart, float* __restrict__ lpart)
{
    const int bid = blockIdx.x;
    const int sp = (bid & 7) >> 2;              // kv half pinned per XCD group
    const int qb = (bid >> 3) * 4 + (bid & 3);  // 0..127
    const int qbase = qb * 64;
    const int kv0 = sp * 4096;
    const int t = threadIdx.x;
    const int w = t >> 6, l = t & 63, lg = l >> 4, ll = l & 15;
    const int wq2 = w & 1, wk4 = w >> 1;        // QK^T decomposition 2q x 4kv

    __shared__ unsigned short Klds[2][64][512];   // 128 KB, src-preswizzled
    __shared__ unsigned short Plds[2][64][64];    // 16 KB, (row>>1)&7 swizzled
    __shared__ float lsum[4][64];

    // TWO Q fragment rows per wave: rows qbase + wq2*32 + {0,16} + ll
    bf16x8 qf[2][16];
    #pragma unroll
    for (int mf = 0; mf < 2; ++mf) {
        const unsigned short* qrow = Qs + (size_t)(qbase + wq2 * 32 + mf * 16 + ll) * 512 + lg * 8;
        #pragma unroll
        for (int ks = 0; ks < 16; ++ks)
            qf[mf][ks] = *(const bf16x8*)(qrow + ks * 32);
    }

    f32x4 oacc[4][4];
    #pragma unroll
    for (int i = 0; i < 4; ++i)
        #pragma unroll
        for (int j = 0; j < 4; ++j) oacc[i][j] = (f32x4){0.f, 0.f, 0.f, 0.f};
    float lrun[2][4];
    #pragma unroll
    for (int i = 0; i < 2; ++i)
        #pragma unroll
        for (int j = 0; j < 4; ++j) lrun[i][j] = 0.f;
    const float scale = 0.044194173824159216f;  // 1/sqrt(512)

    #pragma unroll
    for (int rr = 0; rr < 8; ++rr) {
        const int r = w * 8 + rr;
        gload_lds16(Ks + (size_t)(kv0 + r) * 512 + ((l ^ (r & 7)) << 3),
                    &Klds[0][r][0]);
    }
    __syncthreads();

    for (int it = 0; it < 64; ++it) {
        const int cur = it & 1;
        const int kvb = kv0 + it * 64;

        if (it < 63) {
            const int kvn = kvb + 64;
            #pragma unroll
            for (int rr = 0; rr < 8; ++rr) {
                const int r = w * 8 + rr;
                gload_lds16(Ks + (size_t)(kvn + r) * 512 + ((l ^ (r & 7)) << 3),
                            &Klds[cur ^ 1][r][0]);
            }
        }

        // QK^T: wave (wq2, wk4): q-rows wq2*32..+32, kv-cols wk4*16..+16
        f32x4 sacc[2];
        sacc[0] = (f32x4){0.f, 0.f, 0.f, 0.f};
        sacc[1] = (f32x4){0.f, 0.f, 0.f, 0.f};
        __builtin_amdgcn_s_setprio(1);
        #pragma unroll
        for (int ks = 0; ks < 16; ++ks) {
            const int u = ((ks * 4 + lg) ^ (ll & 7)) * 8;
            bf16x8 kf = *(const bf16x8*)&Klds[cur][wk4 * 16 + ll][u];
            sacc[0] = MFMA16(qf[0][ks], kf, sacc[0]);
            sacc[1] = MFMA16(qf[1][ks], kf, sacc[1]);
        }
        __builtin_amdgcn_s_setprio(0);

        // exp + P write into P[cur]; lrun accumulates per-lane (reduced once
        // after the loop -- d<16 shuffles stay within the lg group)
        #pragma unroll
        for (int mf = 0; mf < 2; ++mf)
            #pragma unroll
            for (int r = 0; r < 4; ++r) {
                const int row = wq2 * 32 + mf * 16 + lg * 4 + r;
                const int swz = (row >> 1) & 7;
                const float p = __expf(sacc[mf][r] * scale);
                const int col = wk4 * 16 + ll;
                const int unit = (col >> 3) ^ swz;
                Plds[cur][row][unit * 8 + (col & 7)] = f2bf(p);
                lrun[mf][r] += p;
            }

        __syncthreads();   // P[cur] ready, K[cur^1] staged

        // PV: wave w owns out-cols w*64..+64, all 64 q-rows
        __builtin_amdgcn_s_setprio(1);
        #pragma unroll
        for (int ks2 = 0; ks2 < 2; ++ks2) {
            bf16x8 vf[4];
            #pragma unroll
            for (int nf = 0; nf < 4; ++nf)
                vf[nf] = *(const bf16x8*)(VsT + (size_t)(w * 64 + nf * 16 + ll) * 8192
                                          + kvb + ks2 * 32 + lg * 8);
            #pragma unroll
            for (int mf = 0; mf < 4; ++mf) {
                const int row = mf * 16 + ll;
                const int unit = (ks2 * 4 + lg) ^ ((row >> 1) & 7);
                bf16x8 pf = *(const bf16x8*)&Plds[cur][row][unit * 8];
                #pragma unroll
                for (int nf = 0; nf < 4; ++nf)
                    oacc[mf][nf] = MFMA16(pf, vf[nf], oacc[mf][nf]);
            }
        }
        __builtin_amdgcn_s_setprio(0);
    }

    const size_t obase = (size_t)sp * 8192 + qbase;
    #pragma unroll
    for (int mf = 0; mf < 4; ++mf)
        #pragma unroll
        for (int r = 0; r < 4; ++r) {
            const size_t row = obase + mf * 16 + lg * 4 + r;
            #pragma unroll
            for (int nf = 0; nf < 4; ++nf)
                Opart[row * 512 + w * 64 + nf * 16 + ll] = oacc[mf][nf][r];
        }

    // deferred softmax row-sum reduce (over the 16 ll lanes)
    #pragma unroll
    for (int mf = 0; mf < 2; ++mf)
        #pragma unroll
        for (int r = 0; r < 4; ++r) {
            float val = lrun[mf][r];
            #pragma unroll
            for (int d = 1; d < 16; d <<= 1) val += __shfl_xor(val, d);
            if (ll == 0)
                lsum[wk4][wq2 * 32 + mf * 16 + lg * 4 + r] = val;
        }
    __syncthreads();
    if (t < 64)
        lpart[(size_t)sp * 8192 + qbase + t] =
            lsum[0][t] + lsum[1][t] + lsum[2][t] + lsum[3][t];
}

// ---------------------------------------------------------------------------
// Merge: out2 = (sum_s Opart[s]) / (sum_s lpart[s]), s in {0,1}
// ---------------------------------------------------------------------------
__global__ __launch_bounds__(256) void merge_kernel(
    const float* __restrict__ Opart, const float* __restrict__ lpart,
    float* __restrict__ out2)
{
    const int idx = blockIdx.x * 256 + threadIdx.x;
    const int q = idx >> 7;
    const int c = (idx & 127) * 4;
    float4_t a = {0.f, 0.f, 0.f, 0.f};
    float ls = 0.f;
    #pragma unroll
    for (int s = 0; s < 2; ++s) {
        float4_t vv = *(const float4_t*)(Opart + ((size_t)s * 8192 + q) * 512 + c);
        a += vv;
        ls += lpart[s * 8192 + q];
    }
    const float inv = 1.f / ls;
    *(float4_t*)(out2 + (size_t)q * 512 + c) = a * inv;
}

extern "C" void kernel_launch(void* const* d_in, const int* in_sizes, int n_in,
                              void* d_out, int out_size, void* d_ws, size_t ws_size,
                              hipStream_t stream)
{
    const float* support = (const float*)d_in[0];
    const float* queries = (const float*)d_in[1];
    const float* Wq = (const float*)d_in[2];
    const float* bq = (const float*)d_in[3];
    const float* Wk = (const float*)d_in[4];
    const float* bk = (const float*)d_in[5];
    const float* Wv = (const float*)d_in[6];
    const float* bv = (const float*)d_in[7];
    const float* gamma = (const float*)d_in[8];
    const float* beta = (const float*)d_in[9];

    float* out = (float*)d_out;
    float* q_proto = out;                       // output 0: [8192,512]
    float* out2 = out + (size_t)8192 * 512;     // output 1: [8192,512]

    char* ws = (char*)d_ws;
    unsigned short* Qs  = (unsigned short*)(ws);                      //  0..8 MB
    unsigned short* Ks  = (unsigned short*)(ws + ((size_t)8 << 20));  //  8..16
    unsigned short* VsT = (unsigned short*)(ws + ((size_t)16 << 20)); // 16..24
    unsigned short* sb  = (unsigned short*)(ws + ((size_t)24 << 20)); // 24..40
    unsigned short* qbuf= (unsigned short*)(ws + ((size_t)40 << 20)); // 40..56
    unsigned short* wqb = (unsigned short*)(ws + ((size_t)56 << 20)); // 56..57
    unsigned short* wkb = (unsigned short*)(ws + ((size_t)57 << 20)); // 57..58
    unsigned short* wvb = (unsigned short*)(ws + ((size_t)58 << 20)); // 58..59
    // Opart aliases sb/qbuf (24..56 MB): proj kernels (sole readers of sb/qbuf)
    // complete before attn writes Opart; cast re-fills sb/qbuf every call.
    float* Opart = (float*)(ws + ((size_t)24 << 20));                 // 32 MB
    float* lpart = (float*)(ws + ((size_t)59 << 20));                 // 64 KB

    cast_kernel<<<8960, 256, 0, stream>>>(support, queries, Wq, Wk, Wv,
                                          sb, qbuf, wqb, wkb, wvb);
    proj_v_kernel<<<256, 512, 0, stream>>>(sb, qbuf, wvb, bv, q_proto, VsT);
    proj_ln_kernel<<<256, 512, 0, stream>>>(sb, qbuf, wkb, bk, wqb, bq,
                                            gamma, beta, Ks, Qs);
    attn_kernel<<<256, 512, 0, stream>>>(Qs, Ks, VsT, Opart, lpart);
    merge_kernel<<<4096, 256, 0, stream>>>(Opart, lpart, out2);
}

// Round 7
// 337.640 us; speedup vs baseline: 1.1876x; 1.0713x over previous
//
#include <hip/hip_runtime.h>
#include <hip/hip_bf16.h>

typedef __attribute__((ext_vector_type(8))) short bf16x8;
typedef __attribute__((ext_vector_type(4))) float f32x4;
typedef __attribute__((ext_vector_type(4))) short short4_t;
typedef __attribute__((ext_vector_type(8))) short short8_t;
typedef __attribute__((ext_vector_type(4))) float float4_t;

#define MFMA16(a, b, c) __builtin_amdgcn_mfma_f32_16x16x32_bf16((a), (b), (c), 0, 0, 0)

__device__ __forceinline__ unsigned short f2bf(float f) {
    unsigned u = __builtin_bit_cast(unsigned, f);
    u += 0x7fffu + ((u >> 16) & 1u);   // round-to-nearest-even
    return (unsigned short)(u >> 16);
}

__device__ __forceinline__ short4_t pack4(float4_t v) {
    short4_t r;
    r[0] = (short)f2bf(v[0]);
    r[1] = (short)f2bf(v[1]);
    r[2] = (short)f2bf(v[2]);
    r[3] = (short)f2bf(v[3]);
    return r;
}

// async global->LDS, 16B per lane. LDS dest is wave-uniform base + lane*16.
__device__ __forceinline__ void gload_lds16(const void* g, void* l) {
    __builtin_amdgcn_global_load_lds(
        (const __attribute__((address_space(1))) unsigned int*)g,
        (__attribute__((address_space(3))) unsigned int*)l, 16, 0, 0);
}

// ---------------------------------------------------------------------------
// cast: f32 -> bf16 for support (8.4M), queries (8.4M), Wq/Wk/Wv (0.5M each).
// ---------------------------------------------------------------------------
__global__ __launch_bounds__(256) void cast_kernel(
    const float* __restrict__ support, const float* __restrict__ queries,
    const float* __restrict__ Wq, const float* __restrict__ Wk,
    const float* __restrict__ Wv,
    unsigned short* __restrict__ sb, unsigned short* __restrict__ qb,
    unsigned short* __restrict__ wqb, unsigned short* __restrict__ wkb,
    unsigned short* __restrict__ wvb)
{
    const size_t e = ((size_t)blockIdx.x * 256 + threadIdx.x) * 8;
    const float* src; unsigned short* dst; size_t off;
    if (e < 8388608)       { src = support; dst = sb;  off = e; }
    else if (e < 16777216) { src = queries; dst = qb;  off = e - 8388608; }
    else if (e < 17301504) { src = Wq;      dst = wqb; off = e - 16777216; }
    else if (e < 17825792) { src = Wk;      dst = wkb; off = e - 17301504; }
    else                   { src = Wv;      dst = wvb; off = e - 17825792; }
    float4_t a = *(const float4_t*)(src + off);
    float4_t b = *(const float4_t*)(src + off + 4);
    short4_t lo = pack4(a), hi = pack4(b);
    short8_t o;
    o[0] = lo[0]; o[1] = lo[1]; o[2] = lo[2]; o[3] = lo[3];
    o[4] = hi[0]; o[5] = hi[1]; o[6] = hi[2]; o[7] = hi[3];
    *(short8_t*)(dst + off) = o;
}

// ---------------------------------------------------------------------------
// proj_v: out = in @ Wv^T + bv, modes {0: queries->q_proto f32, 1: support->
// VsT bf16 transposed}. bf16 inputs, global_load_lds staging (XOR-preswizzle).
// ---------------------------------------------------------------------------
__global__ __launch_bounds__(512, 2) void proj_v_kernel(
    const unsigned short* __restrict__ sb, const unsigned short* __restrict__ qb,
    const unsigned short* __restrict__ wvb, const float* __restrict__ bv,
    float* __restrict__ q_proto, unsigned short* __restrict__ VsT)
{
    const int mode = blockIdx.x >> 7;
    const int rem = blockIdx.x & 127;
    const int rowbase = (rem >> 1) * 128;
    const int colbase = (rem & 1) * 256;
    const unsigned short* A = mode ? sb : qb;

    const int t = threadIdx.x;
    const int w = t >> 6, l = t & 63, lg = l >> 4, ll = l & 15;
    const int wr = w & 1, wc = w >> 1;
    const int sr = l >> 3, su = l & 7;

    __shared__ unsigned short Alds[2][128][64];
    __shared__ unsigned short Blds[2][256][64];

    f32x4 acc[4][4];
    #pragma unroll
    for (int i = 0; i < 4; ++i)
        #pragma unroll
        for (int j = 0; j < 4; ++j) acc[i][j] = (f32x4){0.f, 0.f, 0.f, 0.f};

    #define PV_STAGE(buf, kt)                                                   \
        {                                                                       \
            const int kc = (kt) * 64;                                           \
            _Pragma("unroll")                                                   \
            for (int g = 0; g < 2; ++g) {                                       \
                const int r0 = w * 16 + g * 8, row = r0 + sr;                   \
                gload_lds16(A + (size_t)(rowbase + row) * 1024 + kc             \
                                + ((su ^ (row & 7)) << 3),                      \
                            &Alds[buf][r0][0]);                                 \
            }                                                                   \
            _Pragma("unroll")                                                   \
            for (int g = 0; g < 4; ++g) {                                       \
                const int r0 = w * 32 + g * 8, row = r0 + sr;                   \
                gload_lds16(wvb + (size_t)(colbase + row) * 1024 + kc           \
                                + ((su ^ (row & 7)) << 3),                      \
                            &Blds[buf][r0][0]);                                 \
            }                                                                   \
        }

    PV_STAGE(0, 0)
    __syncthreads();

    for (int kt = 0; kt < 16; ++kt) {
        const int cur = kt & 1;
        if (kt < 15) PV_STAGE(cur ^ 1, kt + 1)
        #pragma unroll
        for (int ks = 0; ks < 2; ++ks) {
            const int u = ((ks * 4 + lg) ^ (ll & 7)) * 8;
            bf16x8 af[4], bfr[4];
            #pragma unroll
            for (int mf = 0; mf < 4; ++mf)
                af[mf] = *(const bf16x8*)&Alds[cur][wr * 64 + mf * 16 + ll][u];
            #pragma unroll
            for (int nf = 0; nf < 4; ++nf)
                bfr[nf] = *(const bf16x8*)&Blds[cur][wc * 64 + nf * 16 + ll][u];
            #pragma unroll
            for (int mf = 0; mf < 4; ++mf)
                #pragma unroll
                for (int nf = 0; nf < 4; ++nf)
                    acc[mf][nf] = MFMA16(af[mf], bfr[nf], acc[mf][nf]);
        }
        __syncthreads();
    }
    #undef PV_STAGE

    float bvv[4];
    #pragma unroll
    for (int nf = 0; nf < 4; ++nf) bvv[nf] = bv[colbase + wc * 64 + nf * 16 + ll];

    if (mode == 0) {
        #pragma unroll
        for (int mf = 0; mf < 4; ++mf)
            #pragma unroll
            for (int r = 0; r < 4; ++r) {
                const size_t row = rowbase + wr * 64 + mf * 16 + lg * 4 + r;
                #pragma unroll
                for (int nf = 0; nf < 4; ++nf)
                    q_proto[row * 512 + colbase + wc * 64 + nf * 16 + ll] = acc[mf][nf][r] + bvv[nf];
            }
    } else {
        #pragma unroll
        for (int mf = 0; mf < 4; ++mf)
            #pragma unroll
            for (int nf = 0; nf < 4; ++nf) {
                float4_t pv = {acc[mf][nf][0] + bvv[nf], acc[mf][nf][1] + bvv[nf],
                               acc[mf][nf][2] + bvv[nf], acc[mf][nf][3] + bvv[nf]};
                const size_t col = colbase + wc * 64 + nf * 16 + ll;
                *(short4_t*)&VsT[col * 8192 + rowbase + wr * 64 + mf * 16 + lg * 4] = pack4(pv);
            }
    }
}

// ---------------------------------------------------------------------------
// proj_ln: dst = LN(in @ W^T + b), modes {0: support/Wk->Ks, 1: queries/Wq->Qs}.
// ---------------------------------------------------------------------------
__global__ __launch_bounds__(512, 2) void proj_ln_kernel(
    const unsigned short* __restrict__ sb, const unsigned short* __restrict__ qb,
    const unsigned short* __restrict__ wkb, const float* __restrict__ bk,
    const unsigned short* __restrict__ wqb, const float* __restrict__ bq,
    const float* __restrict__ gamma, const float* __restrict__ beta,
    unsigned short* __restrict__ Ks, unsigned short* __restrict__ Qs)
{
    const int mode = blockIdx.x >> 7;
    const int rowbase = (blockIdx.x & 127) * 64;
    const unsigned short* A = mode ? qb : sb;
    const unsigned short* W = mode ? wqb : wkb;
    const float* bias = mode ? bq : bk;
    unsigned short* dst = mode ? Qs : Ks;

    const int t = threadIdx.x;
    const int w = t >> 6, l = t & 63, lg = l >> 4, ll = l & 15;
    const int sr = l >> 3, su = l & 7;

    __shared__ unsigned short Alds[2][64][64];
    __shared__ unsigned short Blds[2][512][64];
    __shared__ float red[8][64][2];
    __shared__ float stats[64][2];

    f32x4 acc[4][4];
    #pragma unroll
    for (int i = 0; i < 4; ++i)
        #pragma unroll
        for (int j = 0; j < 4; ++j) acc[i][j] = (f32x4){0.f, 0.f, 0.f, 0.f};

    #define LN_STAGE(buf, kt)                                                   \
        {                                                                       \
            const int kc = (kt) * 64;                                           \
            {                                                                   \
                const int r0 = w * 8, row = r0 + sr;                            \
                gload_lds16(A + (size_t)(rowbase + row) * 1024 + kc             \
                                + ((su ^ (row & 7)) << 3),                      \
                            &Alds[buf][r0][0]);                                 \
            }                                                                   \
            _Pragma("unroll")                                                   \
            for (int g = 0; g < 8; ++g) {                                       \
                const int r0 = w * 64 + g * 8, row = r0 + sr;                   \
                gload_lds16(W + (size_t)row * 1024 + kc                         \
                                + ((su ^ (row & 7)) << 3),                      \
                            &Blds[buf][r0][0]);                                 \
            }                                                                   \
        }

    LN_STAGE(0, 0)
    __syncthreads();

    for (int kt = 0; kt < 16; ++kt) {
        const int cur = kt & 1;
        if (kt < 15) LN_STAGE(cur ^ 1, kt + 1)
        #pragma unroll
        for (int ks = 0; ks < 2; ++ks) {
            const int u = ((ks * 4 + lg) ^ (ll & 7)) * 8;
            bf16x8 af[4], bfr[4];
            #pragma unroll
            for (int mf = 0; mf < 4; ++mf)
                af[mf] = *(const bf16x8*)&Alds[cur][mf * 16 + ll][u];
            #pragma unroll
            for (int nf = 0; nf < 4; ++nf)
                bfr[nf] = *(const bf16x8*)&Blds[cur][w * 64 + nf * 16 + ll][u];
            #pragma unroll
            for (int mf = 0; mf < 4; ++mf)
                #pragma unroll
                for (int nf = 0; nf < 4; ++nf)
                    acc[mf][nf] = MFMA16(af[mf], bfr[nf], acc[mf][nf]);
        }
        __syncthreads();
    }
    #undef LN_STAGE

    float bvv[4];
    #pragma unroll
    for (int nf = 0; nf < 4; ++nf) bvv[nf] = bias[w * 64 + nf * 16 + ll];

    float v[4][4][4];
    #pragma unroll
    for (int mf = 0; mf < 4; ++mf)
        #pragma unroll
        for (int nf = 0; nf < 4; ++nf)
            #pragma unroll
            for (int r = 0; r < 4; ++r)
                v[mf][nf][r] = acc[mf][nf][r] + bvv[nf];

    #pragma unroll
    for (int mf = 0; mf < 4; ++mf)
        #pragma unroll
        for (int r = 0; r < 4; ++r) {
            float s = 0.f, q = 0.f;
            #pragma unroll
            for (int nf = 0; nf < 4; ++nf) { s += v[mf][nf][r]; q += v[mf][nf][r] * v[mf][nf][r]; }
            #pragma unroll
            for (int d = 1; d < 16; d <<= 1) { s += __shfl_xor(s, d); q += __shfl_xor(q, d); }
            if (ll == 0) {
                red[w][mf * 16 + lg * 4 + r][0] = s;
                red[w][mf * 16 + lg * 4 + r][1] = q;
            }
        }
    __syncthreads();
    if (t < 64) {
        float S = 0.f, Q = 0.f;
        #pragma unroll
        for (int w2 = 0; w2 < 8; ++w2) { S += red[w2][t][0]; Q += red[w2][t][1]; }
        const float mu = S * (1.f / 512.f);
        const float var = Q * (1.f / 512.f) - mu * mu;
        stats[t][0] = mu;
        stats[t][1] = rsqrtf(var + 1e-5f);
    }
    __syncthreads();
    float gv[4], bev[4];
    #pragma unroll
    for (int nf = 0; nf < 4; ++nf) {
        gv[nf] = gamma[w * 64 + nf * 16 + ll];
        bev[nf] = beta[w * 64 + nf * 16 + ll];
    }
    #pragma unroll
    for (int mf = 0; mf < 4; ++mf)
        #pragma unroll
        for (int r = 0; r < 4; ++r) {
            const int row = mf * 16 + lg * 4 + r;
            const float mu = stats[row][0], rs = stats[row][1];
            #pragma unroll
            for (int nf = 0; nf < 4; ++nf) {
                const float o = (v[mf][nf][r] - mu) * rs * gv[nf] + bev[nf];
                dst[(size_t)(rowbase + row) * 512 + w * 64 + nf * 16 + ll] = f2bf(o);
            }
        }
}

// ---------------------------------------------------------------------------
// Flash attention v7: v4's proven layout (8 waves, BM=64, BKV=64, QK^T 4q x
// 2kv with qf[16]=64 VGPR, PV 1r x 8c, kv-split 2, VGPR<=128 no-spill) with
// the iteration FUSED: one barrier->barrier region runs PV(it) and QK^T(it+1)
// jammed in a single unrolled loop (2 K-reads + 2 QKT-MFMAs + 2 PV-MFMAs per
// step) so the LDS port and MFMA pipes overlap instead of phasing.
// Prologue peels QK^T(0); epilogue peels PV(63). One __syncthreads per iter.
// ---------------------------------------------------------------------------
__global__ __launch_bounds__(512, 2) void attn_kernel(
    const unsigned short* __restrict__ Qs, const unsigned short* __restrict__ Ks,
    const unsigned short* __restrict__ VsT,
    float* __restrict__ Opart, float* __restrict__ lpart)
{
    const int bid = blockIdx.x;
    const int sp = (bid & 7) >> 2;              // kv half pinned per XCD group
    const int qb = (bid >> 3) * 4 + (bid & 3);  // 0..127
    const int qbase = qb * 64;
    const int kv0 = sp * 4096;
    const int t = threadIdx.x;
    const int w = t >> 6, l = t & 63, lg = l >> 4, ll = l & 15;
    const int wq = w & 3, wk = w >> 2;          // QK^T: 4q x 2kv

    __shared__ unsigned short Klds[2][64][512];   // 128 KB, src-preswizzled
    __shared__ unsigned short Plds[2][64][64];    // 16 KB, (row>>1)&7 swizzled
    __shared__ float lsum[2][64];

    bf16x8 qf[16];
    {
        const unsigned short* qrow = Qs + (size_t)(qbase + wq * 16 + ll) * 512 + lg * 8;
        #pragma unroll
        for (int ks = 0; ks < 16; ++ks)
            qf[ks] = *(const bf16x8*)(qrow + ks * 32);
    }

    f32x4 oacc[4][4];
    #pragma unroll
    for (int i = 0; i < 4; ++i)
        #pragma unroll
        for (int j = 0; j < 4; ++j) oacc[i][j] = (f32x4){0.f, 0.f, 0.f, 0.f};
    float lrun[4] = {0.f, 0.f, 0.f, 0.f};
    const float scale = 0.044194173824159216f;  // 1/sqrt(512)

    #define K_STAGE(buf, kvt)                                                   \
        {                                                                       \
            _Pragma("unroll")                                                   \
            for (int rr = 0; rr < 8; ++rr) {                                    \
                const int r = w * 8 + rr;                                       \
                gload_lds16(Ks + (size_t)((kvt) + r) * 512 + ((l ^ (r & 7)) << 3), \
                            &Klds[buf][r][0]);                                  \
            }                                                                   \
        }

    K_STAGE(0, kv0)
    __syncthreads();
    K_STAGE(1, kv0 + 64)

    // prologue: QK^T(0) + exp -> P[0]
    {
        f32x4 s0 = (f32x4){0.f, 0.f, 0.f, 0.f}, s1 = (f32x4){0.f, 0.f, 0.f, 0.f};
        #pragma unroll
        for (int j = 0; j < 16; ++j) {
            const int u = ((j * 4 + lg) ^ (ll & 7)) * 8;
            bf16x8 ka = *(const bf16x8*)&Klds[0][wk * 32 + ll][u];
            bf16x8 kb = *(const bf16x8*)&Klds[0][wk * 32 + 16 + ll][u];
            s0 = MFMA16(qf[j], ka, s0);
            s1 = MFMA16(qf[j], kb, s1);
        }
        #pragma unroll
        for (int r = 0; r < 4; ++r) {
            const int row = wq * 16 + lg * 4 + r;
            const int swz = (row >> 1) & 7;
            const float p0 = __expf(s0[r] * scale);
            const float p1 = __expf(s1[r] * scale);
            const int c0 = wk * 32 + ll, c1 = c0 + 16;
            Plds[0][row][(((c0 >> 3) ^ swz) << 3) + (c0 & 7)] = f2bf(p0);
            Plds[0][row][(((c1 >> 3) ^ swz) << 3) + (c1 & 7)] = f2bf(p1);
            lrun[r] += p0 + p1;
        }
    }
    __syncthreads();   // P[0] visible; K tile 1 staged (vmcnt drained)

    for (int it = 0; it < 63; ++it) {
        const int cur = it & 1, nxt = cur ^ 1;
        const int kvb = kv0 + it * 64;

        // V for PV(it): issue first (L2 latency hides under early QKT steps)
        bf16x8 vf[2][4];
        #pragma unroll
        for (int ks2 = 0; ks2 < 2; ++ks2)
            #pragma unroll
            for (int nf = 0; nf < 4; ++nf)
                vf[ks2][nf] = *(const bf16x8*)(VsT + (size_t)(w * 64 + nf * 16 + ll) * 8192
                                               + kvb + ks2 * 32 + lg * 8);
        if (it < 62) K_STAGE(cur, kvb + 128)   // K(it+2): buf's last reader was QKT(it)

        // fused: QK^T(it+1) from K[nxt]  ||  PV(it) from P[cur] + vf
        f32x4 s0 = (f32x4){0.f, 0.f, 0.f, 0.f}, s1 = (f32x4){0.f, 0.f, 0.f, 0.f};
        bf16x8 pf;
        __builtin_amdgcn_s_setprio(1);
        #pragma unroll
        for (int j = 0; j < 16; ++j) {
            const int u = ((j * 4 + lg) ^ (ll & 7)) * 8;
            bf16x8 ka = *(const bf16x8*)&Klds[nxt][wk * 32 + ll][u];
            bf16x8 kb = *(const bf16x8*)&Klds[nxt][wk * 32 + 16 + ll][u];
            s0 = MFMA16(qf[j], ka, s0);
            s1 = MFMA16(qf[j], kb, s1);
            #pragma unroll
            for (int s = 0; s < 2; ++s) {
                const int f = 2 * j + s;                 // 0..31
                const int ks2 = f >> 4, mf = (f >> 2) & 3, nf = f & 3;
                if (nf == 0) {
                    const int row = mf * 16 + ll;
                    const int unit = (ks2 * 4 + lg) ^ ((row >> 1) & 7);
                    pf = *(const bf16x8*)&Plds[cur][row][unit * 8];
                }
                oacc[mf][nf] = MFMA16(pf, vf[ks2][nf], oacc[mf][nf]);
            }
        }
        __builtin_amdgcn_s_setprio(0);

        // exp(it+1) -> P[nxt]  (P[nxt]'s last readers were PV(it-1), pre-barrier)
        #pragma unroll
        for (int r = 0; r < 4; ++r) {
            const int row = wq * 16 + lg * 4 + r;
            const int swz = (row >> 1) & 7;
            const float p0 = __expf(s0[r] * scale);
            const float p1 = __expf(s1[r] * scale);
            const int c0 = wk * 32 + ll, c1 = c0 + 16;
            Plds[nxt][row][(((c0 >> 3) ^ swz) << 3) + (c0 & 7)] = f2bf(p0);
            Plds[nxt][row][(((c1 >> 3) ^ swz) << 3) + (c1 & 7)] = f2bf(p1);
            lrun[r] += p0 + p1;
        }
        __syncthreads();   // P[nxt] visible; K(it+2) staged (vmcnt drained)
    }
    #undef K_STAGE

    // epilogue: PV(63) from P[1]
    {
        const int kvb = kv0 + 63 * 64;
        #pragma unroll
        for (int ks2 = 0; ks2 < 2; ++ks2) {
            bf16x8 vf[4];
            #pragma unroll
            for (int nf = 0; nf < 4; ++nf)
                vf[nf] = *(const bf16x8*)(VsT + (size_t)(w * 64 + nf * 16 + ll) * 8192
                                          + kvb + ks2 * 32 + lg * 8);
            #pragma unroll
            for (int mf = 0; mf < 4; ++mf) {
                const int row = mf * 16 + ll;
                const int unit = (ks2 * 4 + lg) ^ ((row >> 1) & 7);
                bf16x8 pf = *(const bf16x8*)&Plds[1][row][unit * 8];
                #pragma unroll
                for (int nf = 0; nf < 4; ++nf)
                    oacc[mf][nf] = MFMA16(pf, vf[nf], oacc[mf][nf]);
            }
        }
    }

    const size_t obase = (size_t)sp * 8192 + qbase;
    #pragma unroll
    for (int mf = 0; mf < 4; ++mf)
        #pragma unroll
        for (int r = 0; r < 4; ++r) {
            const size_t row = obase + mf * 16 + lg * 4 + r;
            #pragma unroll
            for (int nf = 0; nf < 4; ++nf)
                Opart[row * 512 + w * 64 + nf * 16 + ll] = oacc[mf][nf][r];
        }

    // deferred softmax row-sum reduce (over the 16 ll lanes)
    #pragma unroll
    for (int r = 0; r < 4; ++r) {
        float val = lrun[r];
        #pragma unroll
        for (int d = 1; d < 16; d <<= 1) val += __shfl_xor(val, d);
        if (ll == 0)
            lsum[wk][wq * 16 + lg * 4 + r] = val;
    }
    __syncthreads();
    if (t < 64)
        lpart[(size_t)sp * 8192 + qbase + t] = lsum[0][t] + lsum[1][t];
}

// ---------------------------------------------------------------------------
// Merge: out2 = (sum_s Opart[s]) / (sum_s lpart[s]), s in {0,1}
// ---------------------------------------------------------------------------
__global__ __launch_bounds__(256) void merge_kernel(
    const float* __restrict__ Opart, const float* __restrict__ lpart,
    float* __restrict__ out2)
{
    const int idx = blockIdx.x * 256 + threadIdx.x;
    const int q = idx >> 7;
    const int c = (idx & 127) * 4;
    float4_t a = {0.f, 0.f, 0.f, 0.f};
    float ls = 0.f;
    #pragma unroll
    for (int s = 0; s < 2; ++s) {
        float4_t vv = *(const float4_t*)(Opart + ((size_t)s * 8192 + q) * 512 + c);
        a += vv;
        ls += lpart[s * 8192 + q];
    }
    const float inv = 1.f / ls;
    *(float4_t*)(out2 + (size_t)q * 512 + c) = a * inv;
}

extern "C" void kernel_launch(void* const* d_in, const int* in_sizes, int n_in,
                              void* d_out, int out_size, void* d_ws, size_t ws_size,
                              hipStream_t stream)
{
    const float* support = (const float*)d_in[0];
    const float* queries = (const float*)d_in[1];
    const float* Wq = (const float*)d_in[2];
    const float* bq = (const float*)d_in[3];
    const float* Wk = (const float*)d_in[4];
    const float* bk = (const float*)d_in[5];
    const float* Wv = (const float*)d_in[6];
    const float* bv = (const float*)d_in[7];
    const float* gamma = (const float*)d_in[8];
    const float* beta = (const float*)d_in[9];

    float* out = (float*)d_out;
    float* q_proto = out;                       // output 0: [8192,512]
    float* out2 = out + (size_t)8192 * 512;     // output 1: [8192,512]

    char* ws = (char*)d_ws;
    unsigned short* Qs  = (unsigned short*)(ws);                      //  0..8 MB
    unsigned short* Ks  = (unsigned short*)(ws + ((size_t)8 << 20));  //  8..16
    unsigned short* VsT = (unsigned short*)(ws + ((size_t)16 << 20)); // 16..24
    unsigned short* sb  = (unsigned short*)(ws + ((size_t)24 << 20)); // 24..40
    unsigned short* qbuf= (unsigned short*)(ws + ((size_t)40 << 20)); // 40..56
    unsigned short* wqb = (unsigned short*)(ws + ((size_t)56 << 20)); // 56..57
    unsigned short* wkb = (unsigned short*)(ws + ((size_t)57 << 20)); // 57..58
    unsigned short* wvb = (unsigned short*)(ws + ((size_t)58 << 20)); // 58..59
    // Opart aliases sb/qbuf (24..56 MB): proj kernels (sole readers of sb/qbuf)
    // complete before attn writes Opart; cast re-fills sb/qbuf every call.
    float* Opart = (float*)(ws + ((size_t)24 << 20));                 // 32 MB
    float* lpart = (float*)(ws + ((size_t)59 << 20));                 // 64 KB

    cast_kernel<<<8960, 256, 0, stream>>>(support, queries, Wq, Wk, Wv,
                                          sb, qbuf, wqb, wkb, wvb);
    proj_v_kernel<<<256, 512, 0, stream>>>(sb, qbuf, wvb, bv, q_proto, VsT);
    proj_ln_kernel<<<256, 512, 0, stream>>>(sb, qbuf, wkb, bk, wqb, bq,
                                            gamma, beta, Ks, Qs);
    attn_kernel<<<256, 512, 0, stream>>>(Qs, Ks, VsT, Opart, lpart);
    merge_kernel<<<4096, 256, 0, stream>>>(Opart, lpart, out2);
}